// Round 1
// baseline (78.926 us; speedup 1.0000x reference)
//
#include <hip/hip_runtime.h>
#include <stdint.h>

typedef __attribute__((ext_vector_type(8))) short short8;   // bf16x8 MFMA frag (4 VGPR)
typedef __attribute__((ext_vector_type(4))) float f32x4;    // fp32x4 MFMA acc
typedef unsigned short u16;

#define GROUPS 16
#define MROWS  16384
#define NCH    128

__device__ __forceinline__ u16 f2bf(float f) {
    // fp32 -> bf16 round-to-nearest-even (finite inputs only)
    uint32_t u = __float_as_uint(f);
    u += 0x7FFFu + ((u >> 16) & 1u);
    return (u16)(u >> 16);
}

// ---------------------------------------------------------------------------
// Phase 1: build Qt_bf16[g][c][t] = Q[g][t][c], Q = H_0*H_1*...*H_127.
// Rows of Q evolve independently: q_t <- q_t - (q_t . v_i) v_i with
// v_i = w_i * sqrt(2/(w_i.w_i))  (symmetric prescale folds the denominator).
// Grid: (8 row-blocks, 16 groups), 256 threads: 16 rows/block, 16 lanes/row.
// ---------------------------------------------------------------------------
__global__ __launch_bounds__(256) void build_q(const float* __restrict__ w,
                                               u16* __restrict__ qt) {
    __shared__ float wt[128 * 128];   // 64 KiB: wt[i][(r + 4i)&127] = v_i[r]
    const int g   = blockIdx.y;
    const int rb  = blockIdx.x;       // 0..7
    const int tid = threadIdx.x;
    const float* wg = w + (size_t)g * NCH * NCH;   // weight[g][r][i]

    // --- denom for column ci (threads tid and tid+128 compute redundantly)
    const int ci = tid & 127;
    float den = 0.f;
    for (int r = 0; r < 128; r += 4) {
        float a0 = wg[(r + 0) * 128 + ci];
        float a1 = wg[(r + 1) * 128 + ci];
        float a2 = wg[(r + 2) * 128 + ci];
        float a3 = wg[(r + 3) * 128 + ci];
        den += a0 * a0 + a1 * a1 + a2 * a2 + a3 * a3;
    }
    if (tid < 128) wt[tid] = sqrtf(2.0f / den);   // temp scale broadcast
    __syncthreads();
    const float scl = wt[ci];
    __syncthreads();

    // --- stage transposed prescaled reflectors, rotated by 4i floats per row
    {
        const int h = tid >> 7;                   // 0/1
        for (int p = 0; p < 64; ++p) {
            int r = 2 * p + h;
            wt[ci * 128 + ((r + 4 * ci) & 127)] = wg[r * 128 + ci] * scl;
        }
    }
    __syncthreads();

    // --- 128 sequential reflections, pure registers, no barriers
    const int t = rb * 16 + (tid >> 4);   // Q row owned by this lane group
    const int s = tid & 15;               // lane within row; cols 4s+64u+e
    float q[8];
#pragma unroll
    for (int u = 0; u < 2; ++u)
#pragma unroll
        for (int e = 0; e < 4; ++e)
            q[u * 4 + e] = (4 * s + 64 * u + e == t) ? 1.0f : 0.0f;

    const f32x4* wt4 = (const f32x4*)wt;
    for (int i = 0; i < 128; ++i) {
        f32x4 v0 = wt4[i * 32 + ((s + 0  + i) & 31)];   // v_i[4s   .. 4s+3]
        f32x4 v1 = wt4[i * 32 + ((s + 16 + i) & 31)];   // v_i[64+4s .. +3]
        float pa = q[0] * v0.x + q[1] * v0.y + q[2] * v0.z + q[3] * v0.w;
        float pb = q[4] * v1.x + q[5] * v1.y + q[6] * v1.z + q[7] * v1.w;
        pa += pb;
        pa += __shfl_xor(pa, 1);
        pa += __shfl_xor(pa, 2);
        pa += __shfl_xor(pa, 4);
        pa += __shfl_xor(pa, 8);          // full q_t . v_i in all 16 lanes
        q[0] -= pa * v0.x; q[1] -= pa * v0.y; q[2] -= pa * v0.z; q[3] -= pa * v0.w;
        q[4] -= pa * v1.x; q[5] -= pa * v1.y; q[6] -= pa * v1.z; q[7] -= pa * v1.w;
    }

    // --- emit Q^T in bf16: Qt[g][c][t]
    u16* qg = qt + (size_t)g * NCH * NCH;
#pragma unroll
    for (int u = 0; u < 2; ++u)
#pragma unroll
        for (int e = 0; e < 4; ++e)
            qg[(4 * s + 64 * u + e) * 128 + t] = f2bf(q[u * 4 + e]);
}

// ---------------------------------------------------------------------------
// Phase 2: out[g] = x[g] (16384x128 fp32) * Q[g] (128x128), bf16 MFMA.
// Block: 256 threads (4 waves), 64 rows x 128 cols, full K resident in LDS.
// LDS swizzle: byte ^= (row&7)<<4 on the 256-B bf16 rows (T2 pattern).
// ---------------------------------------------------------------------------
__global__ __launch_bounds__(256) void apply_q(const float* __restrict__ x,
                                               const u16* __restrict__ qt,
                                               float* __restrict__ out) {
    __shared__ __align__(16) char smem[64 * 256 + 128 * 256];   // xs 16K + qs 32K
    const int g   = blockIdx.y;
    const int mt  = blockIdx.x;          // 0..255
    const int tid = threadIdx.x;
    const float* xg = x + ((size_t)g * MROWS + (size_t)mt * 64) * NCH;

    // stage x tile: 64 rows x 128 k, fp32 -> bf16, swizzled
#pragma unroll
    for (int p = 0; p < 8; ++p) {
        int f   = tid + 256 * p;
        int row = f >> 5;                // 0..63
        int k4  = f & 31;                // float4 index along k
        f32x4 v = *(const f32x4*)(xg + row * 128 + k4 * 4);
        uint32_t lo = (uint32_t)f2bf(v.x) | ((uint32_t)f2bf(v.y) << 16);
        uint32_t hi = (uint32_t)f2bf(v.z) | ((uint32_t)f2bf(v.w) << 16);
        uint32_t off = (uint32_t)(row * 256) + (((uint32_t)(k4 * 8)) ^ ((row & 7) << 4));
        *(uint2*)(smem + off) = make_uint2(lo, hi);
    }
    // stage Q^T tile: 128 rows(c) x 128 k bf16, swizzled
    const u16* qg = qt + (size_t)g * NCH * NCH;
#pragma unroll
    for (int p = 0; p < 8; ++p) {
        int f   = tid + 256 * p;
        int c   = f >> 4;                // 0..127
        int s16 = f & 15;                // 16-B chunk along k
        uint4 v = *(const uint4*)((const char*)qg + c * 256 + s16 * 16);
        uint32_t off = 16384u + (uint32_t)(c * 256) + (((uint32_t)(s16 * 16)) ^ ((c & 7) << 4));
        *(uint4*)(smem + off) = v;
    }
    __syncthreads();

    const int wv = tid >> 6;             // wave 0..3 -> rows wv*16..+16
    const int l  = tid & 63;
    const int lr = l & 15;
    const int lb = l >> 4;
    const int arow = wv * 16 + lr;

    f32x4 acc[8];
#pragma unroll
    for (int nt = 0; nt < 8; ++nt) { f32x4 z = {0.f, 0.f, 0.f, 0.f}; acc[nt] = z; }

#pragma unroll
    for (int kb = 0; kb < 4; ++kb) {
        int k8 = kb * 32 + lb * 8;       // this lane's 8 contiguous k
        short8 a = *(const short8*)(smem + arow * 256 +
                                    (((uint32_t)(k8 * 2)) ^ ((arow & 7) << 4)));
#pragma unroll
        for (int nt = 0; nt < 8; ++nt) {
            int col = nt * 16 + lr;
            short8 b = *(const short8*)(smem + 16384 + col * 256 +
                                        (((uint32_t)(k8 * 2)) ^ ((col & 7) << 4)));
            acc[nt] = __builtin_amdgcn_mfma_f32_16x16x32_bf16(a, b, acc[nt], 0, 0, 0);
        }
    }

    // epilogue: C/D layout col=lane&15, row=(lane>>4)*4+reg  [m89-verified]
    float* og = out + ((size_t)g * MROWS + (size_t)mt * 64 + wv * 16) * NCH;
#pragma unroll
    for (int nt = 0; nt < 8; ++nt)
#pragma unroll
        for (int r = 0; r < 4; ++r)
            og[(lb * 4 + r) * 128 + nt * 16 + lr] = acc[nt][r];
}

extern "C" void kernel_launch(void* const* d_in, const int* in_sizes, int n_in,
                              void* d_out, int out_size, void* d_ws, size_t ws_size,
                              hipStream_t stream) {
    const float* x = (const float*)d_in[0];
    const float* w = (const float*)d_in[1];
    float* out = (float*)d_out;
    u16* qtw = (u16*)d_ws;               // Qt bf16: 16*128*128*2 = 512 KiB

    build_q<<<dim3(8, GROUPS), 256, 0, stream>>>(w, qtw);
    apply_q<<<dim3(MROWS / 64, GROUPS), 256, 0, stream>>>(x, qtw, out);
}